// Round 1
// 291.648 us; speedup vs baseline: 1.0243x; 1.0243x over previous
//
#include <hip/hip_runtime.h>

typedef short s16x8 __attribute__((ext_vector_type(8)));
typedef short s16x4 __attribute__((ext_vector_type(4)));
typedef float f32x4 __attribute__((ext_vector_type(4)));

__device__ __forceinline__ unsigned short f2bf(float f) {
  unsigned u = __float_as_uint(f);
  u += 0x7fffu + ((u >> 16) & 1u);
  return (unsigned short)(u >> 16);
}
__device__ __forceinline__ float bf2f(unsigned short h) {
  return __uint_as_float(((unsigned)h) << 16);
}

__device__ __forceinline__ f32x4 mfma16_bf16(s16x4 a, s16x4 b, f32x4 c) {
#if __has_builtin(__builtin_amdgcn_mfma_f32_16x16x16bf16_1k)
  return __builtin_amdgcn_mfma_f32_16x16x16bf16_1k(a, b, c, 0, 0, 0);
#else
  asm volatile("v_mfma_f32_16x16x16_bf16 %0, %1, %2, %0" : "+v"(c) : "v"(a), "v"(b));
  return c;
#endif
}

#define GLOAD_LDS16(g, l)                                          \
  __builtin_amdgcn_global_load_lds(                                \
      (const __attribute__((address_space(1))) void*)(g),          \
      (__attribute__((address_space(3))) void*)(l), 16, 0, 0)

// ---------------- prep kernels ----------------

__global__ __launch_bounds__(256) void cvt_x_bf16(const float* __restrict__ in,
                                                  unsigned short* __restrict__ out) {
  int i = (blockIdx.x * 256 + threadIdx.x) * 4;
  float4 v = *(const float4*)(in + i);
  ushort4 o;
  o.x = f2bf(v.x); o.y = f2bf(v.y); o.z = f2bf(v.z); o.w = f2bf(v.w);
  *(ushort4*)(out + i) = o;
}

// W[R][C] fp32 -> Wt[C][R] bf16
__global__ __launch_bounds__(256) void transpose_w(const float* __restrict__ W,
                                                   unsigned short* __restrict__ Wt,
                                                   int R, int C) {
  __shared__ float tile[32][33];
  int c0 = blockIdx.x * 32, r0 = blockIdx.y * 32;
  int x = threadIdx.x, ty = threadIdx.y;
  for (int yy = ty; yy < 32; yy += 8)
    tile[yy][x] = W[(size_t)(r0 + yy) * C + c0 + x];
  __syncthreads();
  for (int yy = ty; yy < 32; yy += 8)
    Wt[(size_t)(c0 + yy) * R + r0 + x] = f2bf(tile[x][yy]);
}

// V section of qkv [B*T][3072] (cols 2048+h*64+d) -> vt[(b*16+h)*64 + d][T]
__global__ __launch_bounds__(256) void transpose_v(const unsigned short* __restrict__ qkv,
                                                   unsigned short* __restrict__ vt) {
  __shared__ unsigned short TT[32][72];
  const int bh = blockIdx.y;
  const int t0 = blockIdx.x * 32;
  const int b = bh >> 4, h = bh & 15;
  const int t = threadIdx.x;
  {
    int row = t >> 3, c8 = (t & 7) * 8;
    const unsigned short* src =
        qkv + (size_t)(b * 2048 + t0 + row) * 3072 + 2048 + h * 64 + c8;
    *(uint4*)&TT[row][c8] = *(const uint4*)src;
  }
  __syncthreads();
  {
    int drow = t >> 2, tc8 = (t & 3) * 8;
    uint4 val;
    unsigned short* vp = (unsigned short*)&val;
    for (int j = 0; j < 8; j++) vp[j] = TT[tc8 + j][drow];
    *(uint4*)(vt + (size_t)(bh * 64 + drow) * 2048 + t0 + tc8) = val;
  }
}

// ---------------- GEMM: C[M][N] = A[M][K] * Bt[N][K]^T + bias ----------------
// m97 structure: 128x128 tile, BK=32, global_load_lds width=16, unpadded LDS.

template <bool OUT_BF16>
__global__ __launch_bounds__(256) void gemm_bt(const unsigned short* __restrict__ A,
                                               const unsigned short* __restrict__ Bt,
                                               const float* __restrict__ bias,
                                               void* __restrict__ Cout,
                                               int M, int N, int K) {
  __shared__ __align__(16) unsigned short As[128 * 32];
  __shared__ __align__(16) unsigned short Bs[128 * 32];

  const int tid  = threadIdx.x;
  const int lane = tid & 63;
  const int w    = tid >> 6;
  const int lr   = lane & 15;
  const int quad = lane >> 4;
  const int wm   = (w >> 1) * 64;
  const int wn   = (w & 1) * 64;
  const int m0   = blockIdx.x * 128;  // x = m: XCD-stable A tiles
  const int n0   = blockIdx.y * 128;

  f32x4 acc[4][4];
  for (int i = 0; i < 4; i++)
    for (int j = 0; j < 4; j++)
      acc[i][j] = f32x4{0.f, 0.f, 0.f, 0.f};

  const int srow = tid >> 2;
  const int scb  = (tid & 3) * 8;
  const unsigned short* Ap = A  + (size_t)(m0 + srow) * K + scb;
  const unsigned short* Bp = Bt + (size_t)(n0 + srow) * K + scb;
  unsigned short* lA0 = As + w * 512;
  unsigned short* lA1 = As + 2048 + w * 512;
  unsigned short* lB0 = Bs + w * 512;
  unsigned short* lB1 = Bs + 2048 + w * 512;

  for (int kk = 0; kk < K; kk += 32) {
    __syncthreads();
    GLOAD_LDS16(Ap + kk, lA0);
    GLOAD_LDS16(Ap + (size_t)64 * K + kk, lA1);
    GLOAD_LDS16(Bp + kk, lB0);
    GLOAD_LDS16(Bp + (size_t)64 * K + kk, lB1);
    __syncthreads();

    s16x8 af[4], bf[4];
    for (int i = 0; i < 4; i++) af[i] = *(const s16x8*)&As[(wm + i * 16 + lr) * 32 + quad * 8];
    for (int j = 0; j < 4; j++) bf[j] = *(const s16x8*)&Bs[(wn + j * 16 + lr) * 32 + quad * 8];
    for (int i = 0; i < 4; i++)
      for (int j = 0; j < 4; j++)
        acc[i][j] = __builtin_amdgcn_mfma_f32_16x16x32_bf16(af[i], bf[j], acc[i][j], 0, 0, 0);
  }

  for (int j = 0; j < 4; j++) {
    int col = n0 + wn + j * 16 + lr;
    float bc = bias[col];
    for (int i = 0; i < 4; i++) {
      int rowb = m0 + wm + i * 16 + quad * 4;
      for (int r = 0; r < 4; r++) {
        float v = acc[i][j][r] + bc;
        if (OUT_BF16)
          ((unsigned short*)Cout)[(size_t)(rowb + r) * N + col] = f2bf(v);
        else
          ((float*)Cout)[(size_t)(rowb + r) * N + col] = v;
      }
    }
  }
}

// ---------------- flash attention v8 ----------------
// 4 waves x 32 q = 128 q per block; grid 1024 -> 4 blocks/CU x 4 waves =
// 16 waves/CU (4/SIMD, 2x v7's occupancy). K/V staged once per 128 q (same L2
// traffic as v7). LDS = [64][64] stride-128B with XOR swizzle
// byte ^= (row&7)<<4: staging uint4 writes, b128 K reads and b64 V reads all
// sit exactly at the wave64 bank floor (verified: 8/8/4 bank-cycles).
// P pack: +0x8000 round bit then v_perm_b32 hi16 pairs (2 perms + 4 adds
// replaces 4x f2bf). S^T = mfma(K,Q) as in v7; PV via 16x16x16, zero LDS
// round-trip for P.

__global__ __launch_bounds__(256, 4) void attn_flash(const unsigned short* __restrict__ qkv,
                                                     const unsigned short* __restrict__ vt,
                                                     unsigned short* __restrict__ y) {
  const int T = 2048, C3 = 3072;
  const int bh = blockIdx.x & 63;
  const int qt = blockIdx.x >> 6;
  const int b  = bh >> 4;
  const int h  = bh & 15;
  const int q0 = qt * 128;

  const int tid  = threadIdx.x;
  const int lane = tid & 63;
  const int w    = tid >> 6;  // 0..3, wave owns q rows q0 + w*32 + [0,32)
  const int lr   = lane & 15;
  const int quad = lane >> 4;

  __shared__ __align__(16) unsigned short Ks[64][64];  // keys x d, XOR-swizzled
  __shared__ __align__(16) unsigned short Vs[64][64];  // d x keys (V^T), XOR-swizzled

  // Q as B-operand: qf[j][c] covers q rows w*32 + j*16 + lr, k-chunk c.
  s16x8 qf[2][2];
  const float QSC = 0.18033688f;  // log2(e)/sqrt(64)
  for (int j = 0; j < 2; j++)
    for (int c = 0; c < 2; c++) {
      const unsigned short* qp =
          qkv + (size_t)(b * T + q0 + w * 32 + j * 16 + lr) * C3 + h * 64 + c * 32 + quad * 8;
      s16x8 t = *(const s16x8*)qp;
      s16x8 o;
      for (int e = 0; e < 8; e++)
        o[e] = (short)f2bf(bf2f((unsigned short)t[e]) * QSC);
      qf[j][c] = o;
    }

  f32x4 O[2][4];  // [q-subtile j][d-tile]; row=q(quad*4+r), col=d(lr)
  for (int j = 0; j < 2; j++)
    for (int dt = 0; dt < 4; dt++) O[j][dt] = f32x4{0.f, 0.f, 0.f, 0.f};
  float l[2] = {0.f, 0.f};  // per-lane partial sum for q = j*16+lr

  const int srow = tid >> 3;       // 0..31
  const int sc8  = (tid & 7) * 8;  // short col 0..56
  const int scb  = sc8 * 2;        // byte col 0..112
  const unsigned short* kbase = qkv + (size_t)(b * T) * C3 + 1024 + (size_t)h * 64;
  const unsigned short* vbase = vt + (size_t)(bh * 64) * 2048;
  char* KsB = (char*)Ks;
  char* VsB = (char*)Vs;
  const int rswz = (lr & 7) << 4;  // read-side XOR (row&7 == lr&7 for all reads)

  for (int kt = 0; kt < 32; kt++) {
    const int k0 = kt * 64;
    __syncthreads();
    for (int rr = 0; rr < 64; rr += 32) {
      int row = srow + rr;
      int sw  = scb ^ ((row & 7) << 4);
      *(uint4*)(KsB + row * 128 + sw) =
          *(const uint4*)(kbase + (size_t)(k0 + row) * C3 + sc8);
      *(uint4*)(VsB + row * 128 + sw) =
          *(const uint4*)(vbase + (size_t)row * 2048 + k0 + sc8);
    }
    __syncthreads();

    for (int i = 0; i < 4; i++) {  // 16-key subtiles
      const char* krow = KsB + (i * 16 + lr) * 128;
      s16x8 kf0 = *(const s16x8*)(krow + ((quad * 16) ^ rswz));
      s16x8 kf1 = *(const s16x8*)(krow + ((64 + quad * 16) ^ rswz));
      s16x4 vf[4];
      for (int dt = 0; dt < 4; dt++)
        vf[dt] = *(const s16x4*)(VsB + (dt * 16 + lr) * 128 + ((i * 32 + quad * 8) ^ rswz));

      for (int j = 0; j < 2; j++) {
        f32x4 S = f32x4{0.f, 0.f, 0.f, 0.f};
        S = __builtin_amdgcn_mfma_f32_16x16x32_bf16(kf0, qf[j][0], S, 0, 0, 0);
        S = __builtin_amdgcn_mfma_f32_16x16x32_bf16(kf1, qf[j][1], S, 0, 0, 0);
        float p0 = __builtin_amdgcn_exp2f(S[0]);
        float p1 = __builtin_amdgcn_exp2f(S[1]);
        float p2 = __builtin_amdgcn_exp2f(S[2]);
        float p3 = __builtin_amdgcn_exp2f(S[3]);
        l[j] += (p0 + p1) + (p2 + p3);
        // pack 4 f32 -> 4 bf16 (round-half-up) via 4 adds + 2 v_perm
        unsigned u0 = __float_as_uint(p0) + 0x8000u;
        unsigned u1 = __float_as_uint(p1) + 0x8000u;
        unsigned u2 = __float_as_uint(p2) + 0x8000u;
        unsigned u3 = __float_as_uint(p3) + 0x8000u;
        union { unsigned u[2]; s16x4 v; } pk;
        pk.u[0] = __builtin_amdgcn_perm(u1, u0, 0x07060302u);
        pk.u[1] = __builtin_amdgcn_perm(u3, u2, 0x07060302u);
        for (int dt = 0; dt < 4; dt++)
          O[j][dt] = mfma16_bf16(pk.v, vf[dt], O[j][dt]);
      }
    }
  }

  // epilogue: reduce l across the 4 quads, redistribute to O's row layout
  for (int j = 0; j < 2; j++) {
    float s = l[j];
    s += __shfl_xor(s, 16, 64);
    s += __shfl_xor(s, 32, 64);
    l[j] = 1.f / s;
  }
  for (int j = 0; j < 2; j++) {
    float inv[4];
    for (int r = 0; r < 4; r++) inv[r] = __shfl(l[j], quad * 4 + r, 64);
    for (int dt = 0; dt < 4; dt++) {
      int col = h * 64 + dt * 16 + lr;
      for (int r = 0; r < 4; r++) {
        int row = b * T + q0 + w * 32 + j * 16 + quad * 4 + r;
        y[(size_t)row * 1024 + col] = f2bf(O[j][dt][r] * inv[r]);
      }
    }
  }
}

// ---------------- launch ----------------

extern "C" void kernel_launch(void* const* d_in, const int* in_sizes, int n_in,
                              void* d_out, int out_size, void* d_ws, size_t ws_size,
                              hipStream_t stream) {
  const float* x  = (const float*)d_in[0];
  const float* Wa = (const float*)d_in[1];
  const float* ba = (const float*)d_in[2];
  const float* Wp = (const float*)d_in[3];
  const float* bp = (const float*)d_in[4];
  float* out = (float*)d_out;

  char* ws = (char*)d_ws;
  unsigned short* xb  = (unsigned short*)ws;                 // 16 MB: x bf16, later y
  unsigned short* Wat = (unsigned short*)(ws + 16777216);    // 6 MB
  unsigned short* Wpt = (unsigned short*)(ws + 23068672);    // 2 MB
  unsigned short* qkv = (unsigned short*)(ws + 25165824);    // 48 MB
  unsigned short* vtr = (unsigned short*)(ws + 75497472);    // 16 MB

  cvt_x_bf16<<<8192, 256, 0, stream>>>(x, xb);
  transpose_w<<<dim3(96, 32), dim3(32, 8), 0, stream>>>(Wa, Wat, 1024, 3072);
  transpose_w<<<dim3(32, 32), dim3(32, 8), 0, stream>>>(Wp, Wpt, 1024, 1024);

  // x = m-tile (64 ≡ 0 mod 8): A-tiles pinned per XCD
  gemm_bt<true><<<dim3(64, 24), 256, 0, stream>>>(xb, Wat, ba, qkv, 8192, 3072, 1024);

  transpose_v<<<dim3(64, 64), 256, 0, stream>>>(qkv, vtr);

  attn_flash<<<1024, 256, 0, stream>>>(qkv, vtr, xb);

  gemm_bt<false><<<dim3(64, 8), 256, 0, stream>>>(xb, Wpt, bp, out, 8192, 1024, 1024);
}

// Round 2
// 283.949 us; speedup vs baseline: 1.0521x; 1.0271x over previous
//
#include <hip/hip_runtime.h>

typedef short s16x8 __attribute__((ext_vector_type(8)));
typedef short s16x4 __attribute__((ext_vector_type(4)));
typedef float f32x4 __attribute__((ext_vector_type(4)));

__device__ __forceinline__ unsigned short f2bf(float f) {
  unsigned u = __float_as_uint(f);
  u += 0x7fffu + ((u >> 16) & 1u);
  return (unsigned short)(u >> 16);
}
__device__ __forceinline__ float bf2f(unsigned short h) {
  return __uint_as_float(((unsigned)h) << 16);
}

#define GLOAD_LDS16(g, l)                                          \
  __builtin_amdgcn_global_load_lds(                                \
      (const __attribute__((address_space(1))) void*)(g),          \
      (__attribute__((address_space(3))) void*)(l), 16, 0, 0)

// ---------------- prep kernels ----------------

__global__ __launch_bounds__(256) void cvt_x_bf16(const float* __restrict__ in,
                                                  unsigned short* __restrict__ out) {
  int i = (blockIdx.x * 256 + threadIdx.x) * 4;
  float4 v = *(const float4*)(in + i);
  ushort4 o;
  o.x = f2bf(v.x); o.y = f2bf(v.y); o.z = f2bf(v.z); o.w = f2bf(v.w);
  *(ushort4*)(out + i) = o;
}

// W[R][C] fp32 -> Wt[C][R] bf16
__global__ __launch_bounds__(256) void transpose_w(const float* __restrict__ W,
                                                   unsigned short* __restrict__ Wt,
                                                   int R, int C) {
  __shared__ float tile[32][33];
  int c0 = blockIdx.x * 32, r0 = blockIdx.y * 32;
  int x = threadIdx.x, ty = threadIdx.y;
  for (int yy = ty; yy < 32; yy += 8)
    tile[yy][x] = W[(size_t)(r0 + yy) * C + c0 + x];
  __syncthreads();
  for (int yy = ty; yy < 32; yy += 8)
    Wt[(size_t)(c0 + yy) * R + r0 + x] = f2bf(tile[x][yy]);
}

// V section of qkv [B*T][3072] (cols 2048+h*64+d) -> vt[(b*16+h)*64 + d][T]
__global__ __launch_bounds__(256) void transpose_v(const unsigned short* __restrict__ qkv,
                                                   unsigned short* __restrict__ vt) {
  __shared__ unsigned short TT[32][72];
  const int bh = blockIdx.y;
  const int t0 = blockIdx.x * 32;
  const int b = bh >> 4, h = bh & 15;
  const int t = threadIdx.x;
  {
    int row = t >> 3, c8 = (t & 7) * 8;
    const unsigned short* src =
        qkv + (size_t)(b * 2048 + t0 + row) * 3072 + 2048 + h * 64 + c8;
    *(uint4*)&TT[row][c8] = *(const uint4*)src;
  }
  __syncthreads();
  {
    int drow = t >> 2, tc8 = (t & 3) * 8;
    uint4 val;
    unsigned short* vp = (unsigned short*)&val;
    for (int j = 0; j < 8; j++) vp[j] = TT[tc8 + j][drow];
    *(uint4*)(vt + (size_t)(bh * 64 + drow) * 2048 + t0 + tc8) = val;
  }
}

// ---------------- GEMM: C[M][N] = A[M][K] * Bt[N][K]^T + bias ----------------
// m97 structure: 128x128 tile, BK=32, global_load_lds width=16, unpadded LDS.

template <bool OUT_BF16>
__global__ __launch_bounds__(256) void gemm_bt(const unsigned short* __restrict__ A,
                                               const unsigned short* __restrict__ Bt,
                                               const float* __restrict__ bias,
                                               void* __restrict__ Cout,
                                               int M, int N, int K) {
  __shared__ __align__(16) unsigned short As[128 * 32];
  __shared__ __align__(16) unsigned short Bs[128 * 32];

  const int tid  = threadIdx.x;
  const int lane = tid & 63;
  const int w    = tid >> 6;
  const int lr   = lane & 15;
  const int quad = lane >> 4;
  const int wm   = (w >> 1) * 64;
  const int wn   = (w & 1) * 64;
  const int m0   = blockIdx.x * 128;  // x = m: XCD-stable A tiles
  const int n0   = blockIdx.y * 128;

  f32x4 acc[4][4];
  for (int i = 0; i < 4; i++)
    for (int j = 0; j < 4; j++)
      acc[i][j] = f32x4{0.f, 0.f, 0.f, 0.f};

  const int srow = tid >> 2;
  const int scb  = (tid & 3) * 8;
  const unsigned short* Ap = A  + (size_t)(m0 + srow) * K + scb;
  const unsigned short* Bp = Bt + (size_t)(n0 + srow) * K + scb;
  unsigned short* lA0 = As + w * 512;
  unsigned short* lA1 = As + 2048 + w * 512;
  unsigned short* lB0 = Bs + w * 512;
  unsigned short* lB1 = Bs + 2048 + w * 512;

  for (int kk = 0; kk < K; kk += 32) {
    __syncthreads();
    GLOAD_LDS16(Ap + kk, lA0);
    GLOAD_LDS16(Ap + (size_t)64 * K + kk, lA1);
    GLOAD_LDS16(Bp + kk, lB0);
    GLOAD_LDS16(Bp + (size_t)64 * K + kk, lB1);
    __syncthreads();

    s16x8 af[4], bf[4];
    for (int i = 0; i < 4; i++) af[i] = *(const s16x8*)&As[(wm + i * 16 + lr) * 32 + quad * 8];
    for (int j = 0; j < 4; j++) bf[j] = *(const s16x8*)&Bs[(wn + j * 16 + lr) * 32 + quad * 8];
    for (int i = 0; i < 4; i++)
      for (int j = 0; j < 4; j++)
        acc[i][j] = __builtin_amdgcn_mfma_f32_16x16x32_bf16(af[i], bf[j], acc[i][j], 0, 0, 0);
  }

  for (int j = 0; j < 4; j++) {
    int col = n0 + wn + j * 16 + lr;
    float bc = bias[col];
    for (int i = 0; i < 4; i++) {
      int rowb = m0 + wm + i * 16 + quad * 4;
      for (int r = 0; r < 4; r++) {
        float v = acc[i][j][r] + bc;
        if (OUT_BF16)
          ((unsigned short*)Cout)[(size_t)(rowb + r) * N + col] = f2bf(v);
        else
          ((float*)Cout)[(size_t)(rowb + r) * N + col] = v;
      }
    }
  }
}

// ---------------- flash attention v9: all-K32 MFMA path ----------------
// 4 waves x 32 q = 128 q per block; grid 1024 -> 4 blocks/CU, 16 waves/CU.
// LDS [64][64] stride-128B, XOR swizzle byte ^= (row&7)<<4 (bank-floor for
// staging writes, K b128 reads, V b128 reads).
//
// v9 changes vs v8:
//  - PV uses 16x16x32 (K=32) instead of legacy 16x16x16: K rows are staged
//    PERMUTED within each 32-key chunk (key = ((r&12)<<1)|((r>>4)<<2)|(r&3))
//    so that after two stacked 16-key QK subtiles each lane's 8 P values are
//    keys quad*8..quad*8+7 in NATURAL order -> V needs no permutation and
//    loads as one b128 per d-tile per chunk. PV MFMA count halves.
//  - l (softmax denom) computed as a 5th PV MFMA against an all-ones
//    B-fragment: D[q][*] = sum_k P[q][k] lands in O's exact accumulator
//    layout -> no VALU l-adds, no epilogue shuffles, and l sums the same
//    bf16-rounded P the numerator uses.

__global__ __launch_bounds__(256, 4) void attn_flash(const unsigned short* __restrict__ qkv,
                                                     const unsigned short* __restrict__ vt,
                                                     unsigned short* __restrict__ y) {
  const int T = 2048, C3 = 3072;
  const int bh = blockIdx.x & 63;
  const int qt = blockIdx.x >> 6;
  const int b  = bh >> 4;
  const int h  = bh & 15;
  const int q0 = qt * 128;

  const int tid  = threadIdx.x;
  const int lane = tid & 63;
  const int w    = tid >> 6;  // 0..3, wave owns q rows q0 + w*32 + [0,32)
  const int lr   = lane & 15;
  const int quad = lane >> 4;

  __shared__ __align__(16) unsigned short Ks[64][64];  // keys x d, XOR-swizzled, K-row-permuted
  __shared__ __align__(16) unsigned short Vs[64][64];  // d x keys (V^T), XOR-swizzled

  // Q as B-operand: qf[j][c] covers q rows w*32 + j*16 + lr, d-chunk c.
  s16x8 qf[2][2];
  const float QSC = 0.18033688f;  // log2(e)/sqrt(64)
  for (int j = 0; j < 2; j++)
    for (int c = 0; c < 2; c++) {
      const unsigned short* qp =
          qkv + (size_t)(b * T + q0 + w * 32 + j * 16 + lr) * C3 + h * 64 + c * 32 + quad * 8;
      s16x8 t = *(const s16x8*)qp;
      s16x8 o;
      for (int e = 0; e < 8; e++)
        o[e] = (short)f2bf(bf2f((unsigned short)t[e]) * QSC);
      qf[j][c] = o;
    }

  s16x8 ones;
  for (int e = 0; e < 8; e++) ones[e] = (short)0x3F80;  // bf16 1.0

  f32x4 O[2][4];   // [q-subtile j][d-tile]; row=q(quad*4+r), col=d(lr)
  f32x4 Lacc[2];   // row-sum accumulator, same row layout as O
  for (int j = 0; j < 2; j++) {
    for (int dt = 0; dt < 4; dt++) O[j][dt] = f32x4{0.f, 0.f, 0.f, 0.f};
    Lacc[j] = f32x4{0.f, 0.f, 0.f, 0.f};
  }

  const int srow = tid >> 3;       // 0..31
  const int sc8  = (tid & 7) * 8;  // short col 0..56
  const int scb  = sc8 * 2;        // byte col 0..112
  const unsigned short* kbase = qkv + (size_t)(b * T) * C3 + 1024 + (size_t)h * 64;
  const unsigned short* vbase = vt + (size_t)(bh * 64) * 2048;
  char* KsB = (char*)Ks;
  char* VsB = (char*)Vs;
  const int rswz = (lr & 7) << 4;  // read-side XOR (row&7 == lr&7 for all reads)

  for (int kt = 0; kt < 32; kt++) {
    const int k0 = kt * 64;
    __syncthreads();
    for (int rr = 0; rr < 64; rr += 32) {
      int row = srow + rr;
      int r32 = row & 31;
      // storage row -> original key, permuted within the 32-key chunk so the
      // 16x16x32 A-fragment (k = quad*8+e) sees keys in natural order
      int key = (row & ~31) | (((r32 & 12) << 1) | ((r32 >> 4) << 2) | (r32 & 3));
      int sw  = scb ^ ((row & 7) << 4);
      *(uint4*)(KsB + row * 128 + sw) =
          *(const uint4*)(kbase + (size_t)(k0 + key) * C3 + sc8);
      *(uint4*)(VsB + row * 128 + sw) =
          *(const uint4*)(vbase + (size_t)row * 2048 + k0 + sc8);
    }
    __syncthreads();

    for (int ch = 0; ch < 2; ch++) {  // 32-key chunks
      const char* krowA = KsB + (ch * 32 + lr) * 128;
      const char* krowB = KsB + (ch * 32 + 16 + lr) * 128;
      s16x8 kA0 = *(const s16x8*)(krowA + ((quad * 16) ^ rswz));
      s16x8 kA1 = *(const s16x8*)(krowA + ((64 + quad * 16) ^ rswz));
      s16x8 kB0 = *(const s16x8*)(krowB + ((quad * 16) ^ rswz));
      s16x8 kB1 = *(const s16x8*)(krowB + ((64 + quad * 16) ^ rswz));
      s16x8 vf[4];
      for (int dt = 0; dt < 4; dt++)
        vf[dt] = *(const s16x8*)(VsB + (dt * 16 + lr) * 128 + ((ch * 64 + quad * 16) ^ rswz));

      for (int j = 0; j < 2; j++) {
        f32x4 Sa = f32x4{0.f, 0.f, 0.f, 0.f};
        f32x4 Sb = f32x4{0.f, 0.f, 0.f, 0.f};
        Sa = __builtin_amdgcn_mfma_f32_16x16x32_bf16(kA0, qf[j][0], Sa, 0, 0, 0);
        Sa = __builtin_amdgcn_mfma_f32_16x16x32_bf16(kA1, qf[j][1], Sa, 0, 0, 0);
        Sb = __builtin_amdgcn_mfma_f32_16x16x32_bf16(kB0, qf[j][0], Sb, 0, 0, 0);
        Sb = __builtin_amdgcn_mfma_f32_16x16x32_bf16(kB1, qf[j][1], Sb, 0, 0, 0);
        // 8 probabilities; pack to bf16 (round-half-up) via 8 adds + 4 v_perm
        unsigned u0 = __float_as_uint(__builtin_amdgcn_exp2f(Sa[0])) + 0x8000u;
        unsigned u1 = __float_as_uint(__builtin_amdgcn_exp2f(Sa[1])) + 0x8000u;
        unsigned u2 = __float_as_uint(__builtin_amdgcn_exp2f(Sa[2])) + 0x8000u;
        unsigned u3 = __float_as_uint(__builtin_amdgcn_exp2f(Sa[3])) + 0x8000u;
        unsigned u4 = __float_as_uint(__builtin_amdgcn_exp2f(Sb[0])) + 0x8000u;
        unsigned u5 = __float_as_uint(__builtin_amdgcn_exp2f(Sb[1])) + 0x8000u;
        unsigned u6 = __float_as_uint(__builtin_amdgcn_exp2f(Sb[2])) + 0x8000u;
        unsigned u7 = __float_as_uint(__builtin_amdgcn_exp2f(Sb[3])) + 0x8000u;
        union { unsigned u[4]; s16x8 v; } pk;
        pk.u[0] = __builtin_amdgcn_perm(u1, u0, 0x07060302u);
        pk.u[1] = __builtin_amdgcn_perm(u3, u2, 0x07060302u);
        pk.u[2] = __builtin_amdgcn_perm(u5, u4, 0x07060302u);
        pk.u[3] = __builtin_amdgcn_perm(u7, u6, 0x07060302u);
        Lacc[j] = __builtin_amdgcn_mfma_f32_16x16x32_bf16(pk.v, ones, Lacc[j], 0, 0, 0);
        for (int dt = 0; dt < 4; dt++)
          O[j][dt] = __builtin_amdgcn_mfma_f32_16x16x32_bf16(pk.v, vf[dt], O[j][dt], 0, 0, 0);
      }
    }
  }

  // epilogue: Lacc rows align with O rows -> no cross-lane traffic
  for (int j = 0; j < 2; j++) {
    for (int r = 0; r < 4; r++) {
      float inv = 1.f / Lacc[j][r];
      int row = b * T + q0 + w * 32 + j * 16 + quad * 4 + r;
      for (int dt = 0; dt < 4; dt++) {
        int col = h * 64 + dt * 16 + lr;
        y[(size_t)row * 1024 + col] = f2bf(O[j][dt][r] * inv);
      }
    }
  }
}

// ---------------- launch ----------------

extern "C" void kernel_launch(void* const* d_in, const int* in_sizes, int n_in,
                              void* d_out, int out_size, void* d_ws, size_t ws_size,
                              hipStream_t stream) {
  const float* x  = (const float*)d_in[0];
  const float* Wa = (const float*)d_in[1];
  const float* ba = (const float*)d_in[2];
  const float* Wp = (const float*)d_in[3];
  const float* bp = (const float*)d_in[4];
  float* out = (float*)d_out;

  char* ws = (char*)d_ws;
  unsigned short* xb  = (unsigned short*)ws;                 // 16 MB: x bf16, later y
  unsigned short* Wat = (unsigned short*)(ws + 16777216);    // 6 MB
  unsigned short* Wpt = (unsigned short*)(ws + 23068672);    // 2 MB
  unsigned short* qkv = (unsigned short*)(ws + 25165824);    // 48 MB
  unsigned short* vtr = (unsigned short*)(ws + 75497472);    // 16 MB

  cvt_x_bf16<<<8192, 256, 0, stream>>>(x, xb);
  transpose_w<<<dim3(96, 32), dim3(32, 8), 0, stream>>>(Wa, Wat, 1024, 3072);
  transpose_w<<<dim3(32, 32), dim3(32, 8), 0, stream>>>(Wp, Wpt, 1024, 1024);

  // x = m-tile (64 ≡ 0 mod 8): A-tiles pinned per XCD
  gemm_bt<true><<<dim3(64, 24), 256, 0, stream>>>(xb, Wat, ba, qkv, 8192, 3072, 1024);

  transpose_v<<<dim3(64, 64), 256, 0, stream>>>(qkv, vtr);

  attn_flash<<<1024, 256, 0, stream>>>(qkv, vtr, xb);

  gemm_bt<false><<<dim3(64, 8), 256, 0, stream>>>(xb, Wpt, bp, out, 8192, 1024, 1024);
}

// Round 3
// 280.098 us; speedup vs baseline: 1.0666x; 1.0137x over previous
//
#include <hip/hip_runtime.h>

typedef short s16x8 __attribute__((ext_vector_type(8)));
typedef short s16x4 __attribute__((ext_vector_type(4)));
typedef float f32x4 __attribute__((ext_vector_type(4)));

__device__ __forceinline__ unsigned short f2bf(float f) {
  unsigned u = __float_as_uint(f);
  u += 0x7fffu + ((u >> 16) & 1u);
  return (unsigned short)(u >> 16);
}
__device__ __forceinline__ float bf2f(unsigned short h) {
  return __uint_as_float(((unsigned)h) << 16);
}

#define GLOAD_LDS16(g, l)                                          \
  __builtin_amdgcn_global_load_lds(                                \
      (const __attribute__((address_space(1))) void*)(g),          \
      (__attribute__((address_space(3))) void*)(l), 16, 0, 0)

// ---------------- prep kernels ----------------

__global__ __launch_bounds__(256) void cvt_x_bf16(const float* __restrict__ in,
                                                  unsigned short* __restrict__ out) {
  int i = (blockIdx.x * 256 + threadIdx.x) * 4;
  float4 v = *(const float4*)(in + i);
  ushort4 o;
  o.x = f2bf(v.x); o.y = f2bf(v.y); o.z = f2bf(v.z); o.w = f2bf(v.w);
  *(ushort4*)(out + i) = o;
}

// W[R][C] fp32 -> Wt[C][R] bf16
__global__ __launch_bounds__(256) void transpose_w(const float* __restrict__ W,
                                                   unsigned short* __restrict__ Wt,
                                                   int R, int C) {
  __shared__ float tile[32][33];
  int c0 = blockIdx.x * 32, r0 = blockIdx.y * 32;
  int x = threadIdx.x, ty = threadIdx.y;
  for (int yy = ty; yy < 32; yy += 8)
    tile[yy][x] = W[(size_t)(r0 + yy) * C + c0 + x];
  __syncthreads();
  for (int yy = ty; yy < 32; yy += 8)
    Wt[(size_t)(c0 + yy) * R + r0 + x] = f2bf(tile[x][yy]);
}

// V section of qkv [B*T][3072] (cols 2048+h*64+d) -> vt[(b*16+h)*64 + d][T]
__global__ __launch_bounds__(256) void transpose_v(const unsigned short* __restrict__ qkv,
                                                   unsigned short* __restrict__ vt) {
  __shared__ unsigned short TT[32][72];
  const int bh = blockIdx.y;
  const int t0 = blockIdx.x * 32;
  const int b = bh >> 4, h = bh & 15;
  const int t = threadIdx.x;
  {
    int row = t >> 3, c8 = (t & 7) * 8;
    const unsigned short* src =
        qkv + (size_t)(b * 2048 + t0 + row) * 3072 + 2048 + h * 64 + c8;
    *(uint4*)&TT[row][c8] = *(const uint4*)src;
  }
  __syncthreads();
  {
    int drow = t >> 2, tc8 = (t & 3) * 8;
    uint4 val;
    unsigned short* vp = (unsigned short*)&val;
    for (int j = 0; j < 8; j++) vp[j] = TT[tc8 + j][drow];
    *(uint4*)(vt + (size_t)(bh * 64 + drow) * 2048 + t0 + tc8) = val;
  }
}

// ---------------- GEMM: C[M][N] = A[M][K] * Bt[N][K]^T + bias ----------------
// m97 structure: 128x128 tile, BK=32, global_load_lds width=16, unpadded LDS.

template <bool OUT_BF16>
__global__ __launch_bounds__(256) void gemm_bt(const unsigned short* __restrict__ A,
                                               const unsigned short* __restrict__ Bt,
                                               const float* __restrict__ bias,
                                               void* __restrict__ Cout,
                                               int M, int N, int K) {
  __shared__ __align__(16) unsigned short As[128 * 32];
  __shared__ __align__(16) unsigned short Bs[128 * 32];

  const int tid  = threadIdx.x;
  const int lane = tid & 63;
  const int w    = tid >> 6;
  const int lr   = lane & 15;
  const int quad = lane >> 4;
  const int wm   = (w >> 1) * 64;
  const int wn   = (w & 1) * 64;
  const int m0   = blockIdx.x * 128;  // x = m: XCD-stable A tiles
  const int n0   = blockIdx.y * 128;

  f32x4 acc[4][4];
  for (int i = 0; i < 4; i++)
    for (int j = 0; j < 4; j++)
      acc[i][j] = f32x4{0.f, 0.f, 0.f, 0.f};

  const int srow = tid >> 2;
  const int scb  = (tid & 3) * 8;
  const unsigned short* Ap = A  + (size_t)(m0 + srow) * K + scb;
  const unsigned short* Bp = Bt + (size_t)(n0 + srow) * K + scb;
  unsigned short* lA0 = As + w * 512;
  unsigned short* lA1 = As + 2048 + w * 512;
  unsigned short* lB0 = Bs + w * 512;
  unsigned short* lB1 = Bs + 2048 + w * 512;

  for (int kk = 0; kk < K; kk += 32) {
    __syncthreads();
    GLOAD_LDS16(Ap + kk, lA0);
    GLOAD_LDS16(Ap + (size_t)64 * K + kk, lA1);
    GLOAD_LDS16(Bp + kk, lB0);
    GLOAD_LDS16(Bp + (size_t)64 * K + kk, lB1);
    __syncthreads();

    s16x8 af[4], bf[4];
    for (int i = 0; i < 4; i++) af[i] = *(const s16x8*)&As[(wm + i * 16 + lr) * 32 + quad * 8];
    for (int j = 0; j < 4; j++) bf[j] = *(const s16x8*)&Bs[(wn + j * 16 + lr) * 32 + quad * 8];
    for (int i = 0; i < 4; i++)
      for (int j = 0; j < 4; j++)
        acc[i][j] = __builtin_amdgcn_mfma_f32_16x16x32_bf16(af[i], bf[j], acc[i][j], 0, 0, 0);
  }

  for (int j = 0; j < 4; j++) {
    int col = n0 + wn + j * 16 + lr;
    float bc = bias[col];
    for (int i = 0; i < 4; i++) {
      int rowb = m0 + wm + i * 16 + quad * 4;
      for (int r = 0; r < 4; r++) {
        float v = acc[i][j][r] + bc;
        if (OUT_BF16)
          ((unsigned short*)Cout)[(size_t)(rowb + r) * N + col] = f2bf(v);
        else
          ((float*)Cout)[(size_t)(rowb + r) * N + col] = v;
      }
    }
  }
}

// ---------------- flash attention v10: dbuf + global_load_lds prefetch ------
// 4 waves x 32 q = 128 q per block; grid 1024 -> 4 blocks/CU, 16 waves/CU.
// All-K32 MFMA path from v9 (K rows staged permuted so PV runs 16x16x32 with
// natural V; softmax denom as a 5th MFMA against all-ones B).
//
// v10 changes vs v9:
//  - Staging via global_load_lds width=16 into a LINEAR LDS slot; the XOR
//    bank-swizzle byte^=((row&7)<<4) moves to the GLOBAL source address
//    (lane l loads short-col ((l&7)^(row&7))*8). Produces the identical LDS
//    image to v9 (same involution both sides), so the read side is unchanged.
//  - Double-buffered K/V (32 KB/block, 4 blocks/CU = 128/160 KB): tile kt+1
//    is issued right after the barrier and flies during tile kt's compute.
//    ONE barrier per tile (its implicit vmcnt(0) drain makes tile kt's loads
//    visible; buf cur^1 was last read in compute kt-1 which finished before
//    this barrier -> race-free).

__global__ __launch_bounds__(256, 4) void attn_flash(const unsigned short* __restrict__ qkv,
                                                     const unsigned short* __restrict__ vt,
                                                     unsigned short* __restrict__ y) {
  const int T = 2048, C3 = 3072;
  const int bh = blockIdx.x & 63;
  const int qt = blockIdx.x >> 6;
  const int b  = bh >> 4;
  const int h  = bh & 15;
  const int q0 = qt * 128;

  const int tid  = threadIdx.x;
  const int lane = tid & 63;
  const int w    = tid >> 6;  // 0..3, wave owns q rows q0 + w*32 + [0,32)
  const int lr   = lane & 15;
  const int quad = lane >> 4;

  __shared__ __align__(16) unsigned short Ks[2][64][64];  // keys x d, swizzled, K-row-permuted
  __shared__ __align__(16) unsigned short Vs[2][64][64];  // d x keys (V^T), swizzled

  // Q as B-operand: qf[j][c] covers q rows w*32 + j*16 + lr, d-chunk c.
  s16x8 qf[2][2];
  const float QSC = 0.18033688f;  // log2(e)/sqrt(64)
  for (int j = 0; j < 2; j++)
    for (int c = 0; c < 2; c++) {
      const unsigned short* qp =
          qkv + (size_t)(b * T + q0 + w * 32 + j * 16 + lr) * C3 + h * 64 + c * 32 + quad * 8;
      s16x8 t = *(const s16x8*)qp;
      s16x8 o;
      for (int e = 0; e < 8; e++)
        o[e] = (short)f2bf(bf2f((unsigned short)t[e]) * QSC);
      qf[j][c] = o;
    }

  s16x8 ones;
  for (int e = 0; e < 8; e++) ones[e] = (short)0x3F80;  // bf16 1.0

  f32x4 O[2][4];   // [q-subtile j][d-tile]; row=q(quad*4+r), col=d(lr)
  f32x4 Lacc[2];   // row-sum accumulator, same row layout as O
  for (int j = 0; j < 2; j++) {
    for (int dt = 0; dt < 4; dt++) O[j][dt] = f32x4{0.f, 0.f, 0.f, 0.f};
    Lacc[j] = f32x4{0.f, 0.f, 0.f, 0.f};
  }

  const int srow = tid >> 3;                       // 0..31
  // pre-swizzled global source col (shorts): lane slot (l&7) XOR row&7
  const int scol = (((tid & 7) ^ (srow & 7)) * 8);
  // K-row permutation within each 32-key chunk (v9): storage row -> key
  const int kperm = (((srow & 12) << 1) | ((srow >> 4) << 2) | (srow & 3));

  const unsigned short* kbase = qkv + (size_t)(b * T) * C3 + 1024 + (size_t)h * 64;
  const unsigned short* vbase = vt + (size_t)(bh * 64) * 2048;
  // per-thread global pointers (advance by tile in the loop via offset)
  const unsigned short* kp0 = kbase + (size_t)(kperm)      * C3 + scol;  // rows 0..31
  const unsigned short* kp1 = kbase + (size_t)(32 + kperm) * C3 + scol;  // rows 32..63
  const unsigned short* vp0 = vbase + (size_t)(srow)      * 2048 + scol;
  const unsigned short* vp1 = vbase + (size_t)(srow + 32) * 2048 + scol;

#define STAGE_KV(bb, k0off)                                                  \
  do {                                                                       \
    GLOAD_LDS16(kp0 + (size_t)(k0off) * C3, &Ks[bb][w * 8][0]);              \
    GLOAD_LDS16(kp1 + (size_t)(k0off) * C3, &Ks[bb][w * 8 + 32][0]);         \
    GLOAD_LDS16(vp0 + (k0off), &Vs[bb][w * 8][0]);                           \
    GLOAD_LDS16(vp1 + (k0off), &Vs[bb][w * 8 + 32][0]);                      \
  } while (0)

  const int rswz = (lr & 7) << 4;  // read-side XOR (row&7 == lr&7 for all reads)

  STAGE_KV(0, 0);
  int cur = 0;
  for (int kt = 0; kt < 32; kt++) {
    __syncthreads();  // implicit vmcnt(0) drain: tile kt's loads visible to all
    if (kt < 31) STAGE_KV(cur ^ 1, (kt + 1) * 64);

    const char* KsB = (const char*)&Ks[cur][0][0];
    const char* VsB = (const char*)&Vs[cur][0][0];

    for (int ch = 0; ch < 2; ch++) {  // 32-key chunks
      const char* krowA = KsB + (ch * 32 + lr) * 128;
      const char* krowB = KsB + (ch * 32 + 16 + lr) * 128;
      s16x8 kA0 = *(const s16x8*)(krowA + ((quad * 16) ^ rswz));
      s16x8 kA1 = *(const s16x8*)(krowA + ((64 + quad * 16) ^ rswz));
      s16x8 kB0 = *(const s16x8*)(krowB + ((quad * 16) ^ rswz));
      s16x8 kB1 = *(const s16x8*)(krowB + ((64 + quad * 16) ^ rswz));
      s16x8 vf[4];
      for (int dt = 0; dt < 4; dt++)
        vf[dt] = *(const s16x8*)(VsB + (dt * 16 + lr) * 128 + ((ch * 64 + quad * 16) ^ rswz));

      for (int j = 0; j < 2; j++) {
        f32x4 Sa = f32x4{0.f, 0.f, 0.f, 0.f};
        f32x4 Sb = f32x4{0.f, 0.f, 0.f, 0.f};
        Sa = __builtin_amdgcn_mfma_f32_16x16x32_bf16(kA0, qf[j][0], Sa, 0, 0, 0);
        Sa = __builtin_amdgcn_mfma_f32_16x16x32_bf16(kA1, qf[j][1], Sa, 0, 0, 0);
        Sb = __builtin_amdgcn_mfma_f32_16x16x32_bf16(kB0, qf[j][0], Sb, 0, 0, 0);
        Sb = __builtin_amdgcn_mfma_f32_16x16x32_bf16(kB1, qf[j][1], Sb, 0, 0, 0);
        // 8 probabilities; pack to bf16 (round-half-up) via 8 adds + 4 v_perm
        unsigned u0 = __float_as_uint(__builtin_amdgcn_exp2f(Sa[0])) + 0x8000u;
        unsigned u1 = __float_as_uint(__builtin_amdgcn_exp2f(Sa[1])) + 0x8000u;
        unsigned u2 = __float_as_uint(__builtin_amdgcn_exp2f(Sa[2])) + 0x8000u;
        unsigned u3 = __float_as_uint(__builtin_amdgcn_exp2f(Sa[3])) + 0x8000u;
        unsigned u4 = __float_as_uint(__builtin_amdgcn_exp2f(Sb[0])) + 0x8000u;
        unsigned u5 = __float_as_uint(__builtin_amdgcn_exp2f(Sb[1])) + 0x8000u;
        unsigned u6 = __float_as_uint(__builtin_amdgcn_exp2f(Sb[2])) + 0x8000u;
        unsigned u7 = __float_as_uint(__builtin_amdgcn_exp2f(Sb[3])) + 0x8000u;
        union { unsigned u[4]; s16x8 v; } pk;
        pk.u[0] = __builtin_amdgcn_perm(u1, u0, 0x07060302u);
        pk.u[1] = __builtin_amdgcn_perm(u3, u2, 0x07060302u);
        pk.u[2] = __builtin_amdgcn_perm(u5, u4, 0x07060302u);
        pk.u[3] = __builtin_amdgcn_perm(u7, u6, 0x07060302u);
        Lacc[j] = __builtin_amdgcn_mfma_f32_16x16x32_bf16(pk.v, ones, Lacc[j], 0, 0, 0);
        for (int dt = 0; dt < 4; dt++)
          O[j][dt] = __builtin_amdgcn_mfma_f32_16x16x32_bf16(pk.v, vf[dt], O[j][dt], 0, 0, 0);
      }
    }
    cur ^= 1;
  }
#undef STAGE_KV

  // epilogue: Lacc rows align with O rows -> no cross-lane traffic
  for (int j = 0; j < 2; j++) {
    for (int r = 0; r < 4; r++) {
      float inv = 1.f / Lacc[j][r];
      int row = b * T + q0 + w * 32 + j * 16 + quad * 4 + r;
      for (int dt = 0; dt < 4; dt++) {
        int col = h * 64 + dt * 16 + lr;
        y[(size_t)row * 1024 + col] = f2bf(O[j][dt][r] * inv);
      }
    }
  }
}

// ---------------- launch ----------------

extern "C" void kernel_launch(void* const* d_in, const int* in_sizes, int n_in,
                              void* d_out, int out_size, void* d_ws, size_t ws_size,
                              hipStream_t stream) {
  const float* x  = (const float*)d_in[0];
  const float* Wa = (const float*)d_in[1];
  const float* ba = (const float*)d_in[2];
  const float* Wp = (const float*)d_in[3];
  const float* bp = (const float*)d_in[4];
  float* out = (float*)d_out;

  char* ws = (char*)d_ws;
  unsigned short* xb  = (unsigned short*)ws;                 // 16 MB: x bf16, later y
  unsigned short* Wat = (unsigned short*)(ws + 16777216);    // 6 MB
  unsigned short* Wpt = (unsigned short*)(ws + 23068672);    // 2 MB
  unsigned short* qkv = (unsigned short*)(ws + 25165824);    // 48 MB
  unsigned short* vtr = (unsigned short*)(ws + 75497472);    // 16 MB

  cvt_x_bf16<<<8192, 256, 0, stream>>>(x, xb);
  transpose_w<<<dim3(96, 32), dim3(32, 8), 0, stream>>>(Wa, Wat, 1024, 3072);
  transpose_w<<<dim3(32, 32), dim3(32, 8), 0, stream>>>(Wp, Wpt, 1024, 1024);

  // x = m-tile (64 ≡ 0 mod 8): A-tiles pinned per XCD
  gemm_bt<true><<<dim3(64, 24), 256, 0, stream>>>(xb, Wat, ba, qkv, 8192, 3072, 1024);

  transpose_v<<<dim3(64, 64), 256, 0, stream>>>(qkv, vtr);

  attn_flash<<<1024, 256, 0, stream>>>(qkv, vtr, xb);

  gemm_bt<false><<<dim3(64, 8), 256, 0, stream>>>(xb, Wpt, bp, out, 8192, 1024, 1024);
}